// Round 2
// baseline (1102.812 us; speedup 1.0000x reference)
//
#include <hip/hip_runtime.h>

#define BLK 128
#define MROWS 32
#define XSTR 168   // X/Y row stride in bf16 elems
#define SSTR 52    // state row stride (floats)

typedef unsigned short u16;
typedef __attribute__((ext_vector_type(8))) short bf16x8;
typedef __attribute__((ext_vector_type(8))) unsigned short u16x8;
typedef __attribute__((ext_vector_type(4))) float f32x4;

struct KArgs { const void* p[29]; void* out; };

__device__ __forceinline__ float b2f(u16 u) { return __uint_as_float(((unsigned)u) << 16); }
__device__ __forceinline__ u16 f2b(float f) {
    unsigned x = __float_as_uint(f);
    return (u16)((x + 0x7FFFu + ((x >> 16) & 1u)) >> 16);   // RNE
}

// Epilogue chunk descriptors: 31 chunks of 8 cols after the 64-wide hand_board.
// kind 0 = embedding copy (p1 = table base row in s_emb), kind 1 = scalar proj (p1 = scalar_W row)
__device__ __constant__ unsigned char EP_KIND[31] = {
    0,0,0,0,0,0,0,0,0,0,0,0, 1,1,1,1, 0,0,0, 1, 0,0,0,0,0, 1,1,1,1,1,1 };
__device__ __constant__ unsigned char EP_P1[31] = {
    40,19,38,38,38,38,38,19,19,19,19,19, 0,2,3,5, 19,26,52, 1, 26,19,52,45,19, 4,4,4,4,4,4 };
__device__ __constant__ unsigned char EP_P2[31] = {
    18,20,22,23,24,25,26,27,28,29,30,31, 40,41,42,43, 35,36,37, 39, 32,33,34,19,38, 44,45,46,47,48,49 };

// dtype probe: under f32 layout u16[100j] = low mantissa half of an exact small
// integer (rank col) -> always 0. Under bf16 layout it's bf16(rank), zero only
// if rank==0 (p=1/14 per sample). flag: 1 = f32 inputs, 0 = bf16 inputs.
__global__ void dtype_probe(const u16* st, int* flag) {
    if (threadIdx.x == 0 && blockIdx.x == 0) {
        unsigned o = 0;
        #pragma unroll
        for (int j = 1; j <= 16; j++) o |= st[100 * j];
        *flag = (o == 0) ? 1 : 0;
    }
}

// One layer chunk: stage W[k][n0..n0+NTILES*16) transposed into LDS (bf16),
// then MFMA (32 rows x NC cols), f32 bias + optional leaky_relu, bf16 to dst.
template<int K, int KMF, int NTILES, bool F32>
__device__ __forceinline__ void layer_chunk(
    const void* Wg, const void* bg, int Nfull, int n0,
    const u16* src, int soff, u16* dst, int doff, bool act,
    u16* s_wt, float* s_bias, int tid)
{
    constexpr int KP = KMF + 8;        // wt row stride
    constexpr int NC = NTILES * 16;
    __syncthreads();                    // previous compute done before clobbering s_wt
    {   // stage weights transposed: s_wt[n][k] = W[k][n0+n]
        for (int i = tid; i < K * NC; i += BLK) {
            int k = i / NC, nn = i % NC;
            int g = k * Nfull + n0 + nn;
            float wv = F32 ? ((const float*)Wg)[g] : b2f(((const u16*)Wg)[g]);
            s_wt[nn * KP + k] = f2b(wv);
        }
        if constexpr (KMF > K) {                    // zero K-padding rows
            for (int i = tid; i < (KMF - K) * NC; i += BLK) {
                int k = K + i / NC, nn = i % NC;
                s_wt[nn * KP + k] = 0;
            }
        }
        if (tid < NC)
            s_bias[tid] = F32 ? ((const float*)bg)[n0 + tid] : b2f(((const u16*)bg)[n0 + tid]);
    }
    __syncthreads();
    {
        const int lane = tid & 63, wave = tid >> 6;
        const int m = lane & 15, q = lane >> 4;
        f32x4 acc[NTILES] = {};
        #pragma unroll
        for (int kk = 0; kk < KMF; kk += 32) {
            // A frag: A[m][k], k = kk + q*8 + j  (contiguous 16B)
            bf16x8 a = *(const bf16x8*)&src[(wave * 16 + m) * XSTR + soff + kk + q * 8];
            #pragma unroll
            for (int t = 0; t < NTILES; t++) {
                // B frag: B[k][n] from transposed wt[n][k]
                bf16x8 b = *(const bf16x8*)&s_wt[(t * 16 + m) * KP + kk + q * 8];
                acc[t] = __builtin_amdgcn_mfma_f32_16x16x32_bf16(a, b, acc[t], 0, 0, 0);
            }
        }
        #pragma unroll
        for (int t = 0; t < NTILES; t++) {
            float bias = s_bias[t * 16 + m];
            int col = doff + n0 + t * 16 + m;       // D col = lane&15
            #pragma unroll
            for (int i = 0; i < 4; i++) {
                int r = wave * 16 + q * 4 + i;      // D row = quad*4 + reg
                float v = acc[t][i] + bias;
                if (act) v = (v > 0.f) ? v : 0.01f * v;
                dst[r * XSTR + col] = f2b(v);
            }
        }
    }
}

template<bool F32>
__global__ __launch_bounds__(BLK, 1) void poker_fused(KArgs a, const int* flag)
{
    if (*flag != (F32 ? 1 : 0)) return;   // wrong-dtype instantiation: exit

    __shared__ alignas(16) float s_state[MROWS * SSTR];
    __shared__ alignas(16) float s_emb[54 * 8];  // suit0 rank5 pos19 act26 actv38 street40 nump45 blind52
    __shared__ alignas(16) float s_scalW[48];
    __shared__ alignas(16) float s_scalB[48];
    __shared__ alignas(16) float s_bias[160];
    __shared__ alignas(16) u16   s_X[MROWS * XSTR];
    __shared__ alignas(16) u16   s_Y[MROWS * XSTR];
    __shared__ alignas(16) u16   s_wt[80 * 168];    // max chunk: 80 cols x KP=168

    const int tid = threadIdx.x;
    const long row0 = (long)blockIdx.x * MROWS;

    // ---- stage state as f32 (coalesced)
    if constexpr (F32) {
        const float* g = (const float*)a.p[0] + row0 * 50;
        for (int i = tid; i < MROWS * 50; i += BLK)
            s_state[(i / 50) * SSTR + i % 50] = g[i];
    } else {
        const u16* g = (const u16*)a.p[0] + row0 * 50;
        for (int i = tid; i < MROWS * 50; i += BLK)
            s_state[(i / 50) * SSTR + i % 50] = b2f(g[i]);
    }
    // ---- stage embedding tables as f32
    {
        const void* srcs[8] = { a.p[1], a.p[2], a.p[21], a.p[22], a.p[23], a.p[24], a.p[25], a.p[26] };
        const int  cnt[8]  = { 5, 14, 7, 12, 2, 5, 7, 2 };
        int base = 0;
        for (int t = 0; t < 8; t++) {
            int n = cnt[t] * 8;
            for (int i = tid; i < n; i += BLK)
                s_emb[base + i] = F32 ? ((const float*)srcs[t])[i] : b2f(((const u16*)srcs[t])[i]);
            base += n;
        }
    }
    if (tid < 48) {
        s_scalW[tid] = F32 ? ((const float*)a.p[27])[tid] : b2f(((const u16*)a.p[27])[tid]);
        s_scalB[tid] = F32 ? ((const float*)a.p[28])[tid] : b2f(((const u16*)a.p[28])[tid]);
    }
    __syncthreads();

    // ---- zero K-pad cols [144,168) of both buffers
    for (int i = tid; i < MROWS * 24; i += BLK) {
        int r = i / 24, c = 144 + i % 24;
        s_X[r * XSTR + c] = 0; s_Y[r * XSTR + c] = 0;
    }
    // ---- gather card embeddings: X = [hand(4x16) | board(5x16)]; per card [suit(8)|rank(8)]
    for (int u = tid; u < MROWS * 9; u += BLK) {
        int r = u / 9, cd = u % 9;
        int rkc, stc, db;
        if (cd < 4) { rkc = 2 * cd;      stc = 2 * cd + 1; db = r * XSTR + cd * 16; }
        else { int c2 = cd - 4; rkc = 8 + 2 * c2; stc = 9 + 2 * c2; db = r * XSTR + 64 + c2 * 16; }
        int st = (int)(s_state[r * SSTR + stc] + 0.5f);
        int rk = (int)(s_state[r * SSTR + rkc] + 0.5f);
        #pragma unroll
        for (int j = 0; j < 8; j++) {
            s_X[db + j]     = f2b(s_emb[st * 8 + j]);
            s_X[db + 8 + j] = f2b(s_emb[(5 + rk) * 8 + j]);
        }
    }

    // ---- fused MLP chain (ping-pong X<->Y; board lives at col offset 64)
    layer_chunk<64,  64, 4, F32>(a.p[3],  a.p[4],  64,  0,  s_X, 0,  s_Y, 0,  true,  s_wt, s_bias, tid); // hand L1
    layer_chunk<80,  96, 5, F32>(a.p[9],  a.p[10], 80,  0,  s_X, 64, s_Y, 64, true,  s_wt, s_bias, tid); // board L1
    layer_chunk<64,  64, 4, F32>(a.p[5],  a.p[6],  64,  0,  s_Y, 0,  s_X, 0,  true,  s_wt, s_bias, tid); // hand L2
    layer_chunk<80,  96, 5, F32>(a.p[11], a.p[12], 80,  0,  s_Y, 64, s_X, 64, true,  s_wt, s_bias, tid); // board L2
    layer_chunk<64,  64, 4, F32>(a.p[7],  a.p[8],  64,  0,  s_X, 0,  s_Y, 0,  false, s_wt, s_bias, tid); // hand L3
    layer_chunk<80,  96, 5, F32>(a.p[13], a.p[14], 80,  0,  s_X, 64, s_Y, 64, false, s_wt, s_bias, tid); // board L3
    // Y[0:144] = concat(hand, board); Y[144:160] = 0
    layer_chunk<144,160, 5, F32>(a.p[15], a.p[16], 144, 0,  s_Y, 0,  s_X, 0,  true,  s_wt, s_bias, tid); // hb L1a
    layer_chunk<144,160, 4, F32>(a.p[15], a.p[16], 144, 80, s_Y, 0,  s_X, 0,  true,  s_wt, s_bias, tid); // hb L1b
    layer_chunk<144,160, 4, F32>(a.p[17], a.p[18], 64,  0,  s_X, 0,  s_Y, 0,  true,  s_wt, s_bias, tid); // hb L2
    layer_chunk<64,  64, 4, F32>(a.p[19], a.p[20], 64,  0,  s_Y, 0,  s_X, 0,  false, s_wt, s_bias, tid); // hb L3
    __syncthreads();

    // ---- epilogue: 312 cols = 39 chunks x 8
    for (int u = tid; u < MROWS * 39; u += BLK) {
        int r = u / 39, c = u % 39;
        float v[8];
        if (c < 8) {
            #pragma unroll
            for (int j = 0; j < 8; j++) v[j] = b2f(s_X[r * XSTR + c * 8 + j]);   // hand_board
        } else {
            int e = c - 8;
            int col = EP_P2[e], p1 = EP_P1[e];
            if (EP_KIND[e] == 0) {
                int idx = (int)(s_state[r * SSTR + col] + 0.5f);
                #pragma unroll
                for (int j = 0; j < 8; j++) v[j] = s_emb[(p1 + idx) * 8 + j];
            } else {
                float s = s_state[r * SSTR + col];
                #pragma unroll
                for (int j = 0; j < 8; j++) v[j] = fmaf(s, s_scalW[p1 * 8 + j], s_scalB[p1 * 8 + j]);
            }
        }
        long base = (row0 + r) * 312 + c * 8;
        if constexpr (F32) {
            float* o = (float*)a.out;
            f32x4 lo = { v[0], v[1], v[2], v[3] };
            f32x4 hi = { v[4], v[5], v[6], v[7] };
            *(f32x4*)&o[base]     = lo;
            *(f32x4*)&o[base + 4] = hi;
        } else {
            u16x8 w;
            #pragma unroll
            for (int j = 0; j < 8; j++) w[j] = f2b(v[j]);
            *(u16x8*)&((u16*)a.out)[base] = w;
        }
    }
}

extern "C" void kernel_launch(void* const* d_in, const int* in_sizes, int n_in,
                              void* d_out, int out_size, void* d_ws, size_t ws_size,
                              hipStream_t stream) {
    KArgs args;
    for (int i = 0; i < 29; i++) args.p[i] = d_in[i];
    args.out = d_out;
    int rows = in_sizes[0] / 50;          // 262144
    int blocks = rows / MROWS;            // 8192
    int* flag = (int*)d_ws;
    dtype_probe<<<dim3(1), dim3(64), 0, stream>>>((const u16*)d_in[0], flag);
    poker_fused<false><<<dim3(blocks), dim3(BLK), 0, stream>>>(args, flag);
    poker_fused<true ><<<dim3(blocks), dim3(BLK), 0, stream>>>(args, flag);
}

// Round 3
// 609.724 us; speedup vs baseline: 1.8087x; 1.8087x over previous
//
#include <hip/hip_runtime.h>

#define BLK 128
#define XSTR 168   // X/Y row stride in bf16 elems (16B-aligned rows; bank-optimal)

typedef unsigned short u16;
typedef __attribute__((ext_vector_type(8)))  short bf16x8;
typedef __attribute__((ext_vector_type(8)))  unsigned short u16x8;
typedef __attribute__((ext_vector_type(4)))  unsigned short u16x4;
typedef __attribute__((ext_vector_type(4)))  float f32x4;
typedef __attribute__((ext_vector_type(16))) float f32x16;

struct KArgs { const void* p[29]; void* out; };

__device__ __forceinline__ float b2f(u16 u) { return __uint_as_float(((unsigned)u) << 16); }
__device__ __forceinline__ u16 f2b(float f) {
    unsigned x = __float_as_uint(f);
    return (u16)((x + 0x7FFFu + ((x >> 16) & 1u)) >> 16);   // RNE
}

// ---- epilogue chunk descriptors (verified R2): 31 chunks of 8 cols after hand_board
__device__ __constant__ unsigned char EP_KIND[31] = {
    0,0,0,0,0,0,0,0,0,0,0,0, 1,1,1,1, 0,0,0, 1, 0,0,0,0,0, 1,1,1,1,1,1 };
__device__ __constant__ unsigned char EP_P1[31] = {
    40,19,38,38,38,38,38,19,19,19,19,19, 0,2,3,5, 19,26,52, 1, 26,19,52,45,19, 4,4,4,4,4,4 };
__device__ __constant__ unsigned char EP_P2[31] = {
    18,20,22,23,24,25,26,27,28,29,30,31, 40,41,42,43, 35,36,37, 39, 32,33,34,19,38, 44,45,46,47,48,49 };

// ---- weight-arena layout (bf16, transposed wt[n][k], KP = K+8, N padded to mult-32)
__device__ __constant__ int PL_K[9]    = {64,80,64,80,64,80,144,144,64};
__device__ __constant__ int PL_N[9]    = {64,80,64,80,64,80,144,64,64};
__device__ __constant__ int PL_NC[9]   = {64,96,64,96,64,96,160,64,64};
__device__ __constant__ int PL_WOFF[9] = {0,4608,13056,17664,26112,30720,39168,63488,73216};
__device__ __constant__ int PL_BOFF[9] = {0,64,160,224,320,384,480,640,704};
__device__ __constant__ int PL_WIDX[9] = {3,9,5,11,7,13,15,17,19};
#define ARENA_ELEMS 77824
#define BIAS_BYTE_OFF 155648          // = ARENA_ELEMS*2, 16B aligned
#define FLAG_BYTE_OFF 158720          // after 768 bias floats

// dtype probe (verified R2): f32 layout -> these u16 positions are all zero
__global__ void dtype_probe(const u16* st, int* flag) {
    if (threadIdx.x == 0 && blockIdx.x == 0) {
        unsigned o = 0;
        #pragma unroll
        for (int j = 1; j <= 16; j++) o |= st[100 * j];
        *flag = (o == 0) ? 1 : 0;
    }
}

template<bool F32>
__global__ void poker_prep(KArgs a, u16* arena, float* biasar, const int* flag)
{
    if (*flag != (F32 ? 1 : 0)) return;
    const int L = blockIdx.x;
    const int K = PL_K[L], N = PL_N[L], NC = PL_NC[L], KP = K + 8;
    const void* W = a.p[PL_WIDX[L]];
    const void* b = a.p[PL_WIDX[L] + 1];
    u16* wt = arena + PL_WOFF[L];
    for (int e = threadIdx.x; e < NC * KP; e += blockDim.x) {
        int n = e / KP, k = e - n * KP;
        float v = 0.f;
        if (k < K && n < N)
            v = F32 ? ((const float*)W)[k * N + n] : b2f(((const u16*)W)[k * N + n]);
        wt[e] = f2b(v);
    }
    if ((int)threadIdx.x < NC) {
        float v = ((int)threadIdx.x < N)
            ? (F32 ? ((const float*)b)[threadIdx.x] : b2f(((const u16*)b)[threadIdx.x]))
            : 0.f;
        biasar[PL_BOFF[L] + threadIdx.x] = v;
    }
}

// One full layer for one wave's 32 rows. Operand-swapped MFMA:
//   A = wt[n_out][k]  (m = n_out = lane&31, k = (lane>>5)*8 + j)
//   B = X^T           (n = x-row = lane&31, k contiguous)  -> D col = x-row
//   D row = n_out = (reg&3) + 8*(reg>>2) + 4*(lane>>5)  -> regs 4g..4g+3 = 4 consecutive n_out
template<int K, int NT>
__device__ __forceinline__ void layer(
    const u16* __restrict__ wt, const float* __restrict__ bias,
    const u16* src, int soff, u16* dst, int doff, bool act,
    int lane, int rbase)
{
    constexpr int KP = K + 8;
    const int h = lane >> 5, n32 = lane & 31;
    const u16* xp = src + (rbase + n32) * XSTR + soff + h * 8;
    const u16* wp = wt + n32 * KP + h * 8;
    f32x16 acc[NT] = {};
    #pragma unroll
    for (int kk = 0; kk < K; kk += 16) {
        bf16x8 xf = *(const bf16x8*)(xp + kk);
        #pragma unroll
        for (int t = 0; t < NT; t++) {
            bf16x8 wf = *(const bf16x8*)(wp + t * 32 * KP + kk);
            acc[t] = __builtin_amdgcn_mfma_f32_32x32x16_bf16(wf, xf, acc[t], 0, 0, 0);
        }
    }
    u16* dp = dst + (rbase + n32) * XSTR + doff + 4 * h;
    #pragma unroll
    for (int t = 0; t < NT; t++) {
        #pragma unroll
        for (int g = 0; g < 4; g++) {
            f32x4 bv = *(const f32x4*)(bias + t * 32 + 8 * g + 4 * h);
            u16x4 pk;
            #pragma unroll
            for (int j = 0; j < 4; j++) {
                float v = acc[t][4 * g + j] + bv[j];
                if (act) v = (v > 0.f) ? v : 0.01f * v;
                pk[j] = f2b(v);
            }
            *(u16x4*)(dp + t * 32 + 8 * g) = pk;    // ds_write_b64, bank-clean at XSTR=168
        }
    }
}

template<bool F32>
__global__ __launch_bounds__(BLK, 2) void poker_main(
    KArgs a, const u16* __restrict__ arena, const float* __restrict__ biasar, const int* flag)
{
    if (*flag != (F32 ? 1 : 0)) return;

    __shared__ alignas(16) u16   s_emb[54 * 8];   // bf16 rows: suit0 rank5 pos19 act26 actv38 street40 nump45 blind52
    __shared__ alignas(16) float s_scalW[48];
    __shared__ alignas(16) float s_scalB[48];
    __shared__ alignas(16) u16   s_X[64 * XSTR];
    __shared__ alignas(16) u16   s_Y[64 * XSTR];

    const int tid = threadIdx.x;
    const int lane = tid & 63, wave = tid >> 6;
    const int rbase = wave * 32;
    const long row0 = (long)blockIdx.x * 64;

    // ---- block-wide staging of tiny tables (the only barrier in the kernel)
    {
        const void* srcs[8] = { a.p[1], a.p[2], a.p[21], a.p[22], a.p[23], a.p[24], a.p[25], a.p[26] };
        const int  cnt[8]   = { 5, 14, 7, 12, 2, 5, 7, 2 };
        int base = 0;
        for (int t = 0; t < 8; t++) {
            int n = cnt[t] * 8;
            for (int i = tid; i < n; i += BLK)
                s_emb[base + i] = F32 ? f2b(((const float*)srcs[t])[i]) : ((const u16*)srcs[t])[i];
            base += n;
        }
        if (tid < 48) {
            s_scalW[tid] = F32 ? ((const float*)a.p[27])[tid] : b2f(((const u16*)a.p[27])[tid]);
            s_scalB[tid] = F32 ? ((const float*)a.p[28])[tid] : b2f(((const u16*)a.p[28])[tid]);
        }
    }
    __syncthreads();

    // ---- per-wave card gather into s_X: [hand 4x16 | board 5x16], card = [suit8|rank8]
    for (int u = lane; u < 32 * 9; u += 64) {
        int r = u / 9, cd = u - 9 * r;
        int rkc, stc, db;
        if (cd < 4) { rkc = 2 * cd;      stc = 2 * cd + 1; db = (rbase + r) * XSTR + cd * 16; }
        else { int c2 = cd - 4; rkc = 8 + 2 * c2; stc = 9 + 2 * c2; db = (rbase + r) * XSTR + 64 + c2 * 16; }
        long grow = row0 + rbase + r;
        float fs, fr;
        if constexpr (F32) {
            const float* gs = (const float*)a.p[0] + grow * 50;
            fs = gs[stc]; fr = gs[rkc];
        } else {
            const u16* gs = (const u16*)a.p[0] + grow * 50;
            fs = b2f(gs[stc]); fr = b2f(gs[rkc]);
        }
        int st = (int)(fs + 0.5f), rk = (int)(fr + 0.5f);
        *(u16x8*)&s_X[db]     = *(const u16x8*)&s_emb[st * 8];
        *(u16x8*)&s_X[db + 8] = *(const u16x8*)&s_emb[(5 + rk) * 8];
    }

    // ---- 9 layers, wave-private rows, no barriers (same-wave LDS ordering via lgkmcnt)
    layer< 64, 2>(arena + 0,     biasar + 0,   s_X, 0,  s_Y, 0,  true,  lane, rbase); // hand L1
    layer< 80, 3>(arena + 4608,  biasar + 64,  s_X, 64, s_Y, 64, true,  lane, rbase); // board L1
    layer< 64, 2>(arena + 13056, biasar + 160, s_Y, 0,  s_X, 0,  true,  lane, rbase); // hand L2
    layer< 80, 3>(arena + 17664, biasar + 224, s_Y, 64, s_X, 64, true,  lane, rbase); // board L2
    layer< 64, 2>(arena + 26112, biasar + 320, s_X, 0,  s_Y, 0,  false, lane, rbase); // hand L3
    layer< 80, 3>(arena + 30720, biasar + 384, s_X, 64, s_Y, 64, false, lane, rbase); // board L3
    layer<144, 5>(arena + 39168, biasar + 480, s_Y, 0,  s_X, 0,  true,  lane, rbase); // hb L1
    layer<144, 2>(arena + 63488, biasar + 640, s_X, 0,  s_Y, 0,  true,  lane, rbase); // hb L2
    layer< 64, 2>(arena + 73216, biasar + 704, s_Y, 0,  s_X, 0,  false, lane, rbase); // hb L3

    // ---- per-wave epilogue: 312 cols = 39 chunks x 8, coalesced 32B (f32) stores
    for (int u = lane; u < 32 * 39; u += 64) {
        int r = u / 39, c = u - 39 * r;
        long grow = row0 + rbase + r;
        float v[8];
        if (c < 8) {
            u16x8 w = *(const u16x8*)&s_X[(rbase + r) * XSTR + c * 8];  // hand_board
            #pragma unroll
            for (int j = 0; j < 8; j++) v[j] = b2f(w[j]);
        } else {
            int e = c - 8;
            int col = EP_P2[e], p1 = EP_P1[e];
            float sv;
            if constexpr (F32) sv = ((const float*)a.p[0])[grow * 50 + col];
            else               sv = b2f(((const u16*)a.p[0])[grow * 50 + col]);
            if (EP_KIND[e] == 0) {
                int idx = (int)(sv + 0.5f);
                u16x8 w = *(const u16x8*)&s_emb[(p1 + idx) * 8];
                #pragma unroll
                for (int j = 0; j < 8; j++) v[j] = b2f(w[j]);
            } else {
                #pragma unroll
                for (int j = 0; j < 8; j++) v[j] = fmaf(sv, s_scalW[p1 * 8 + j], s_scalB[p1 * 8 + j]);
            }
        }
        long base = grow * 312 + c * 8;
        if constexpr (F32) {
            float* o = (float*)a.out;
            f32x4 lo = { v[0], v[1], v[2], v[3] };
            f32x4 hi = { v[4], v[5], v[6], v[7] };
            *(f32x4*)&o[base]     = lo;
            *(f32x4*)&o[base + 4] = hi;
        } else {
            u16x8 w;
            #pragma unroll
            for (int j = 0; j < 8; j++) w[j] = f2b(v[j]);
            *(u16x8*)&((u16*)a.out)[base] = w;
        }
    }
}

extern "C" void kernel_launch(void* const* d_in, const int* in_sizes, int n_in,
                              void* d_out, int out_size, void* d_ws, size_t ws_size,
                              hipStream_t stream) {
    KArgs args;
    for (int i = 0; i < 29; i++) args.p[i] = d_in[i];
    args.out = d_out;
    u16*   arena  = (u16*)d_ws;
    float* biasar = (float*)((char*)d_ws + BIAS_BYTE_OFF);
    int*   flag   = (int*)((char*)d_ws + FLAG_BYTE_OFF);
    int rows = in_sizes[0] / 50;          // 262144
    int blocks = rows / 64;               // 4096

    dtype_probe<<<dim3(1), dim3(64), 0, stream>>>((const u16*)d_in[0], flag);
    poker_prep<false><<<dim3(9), dim3(256), 0, stream>>>(args, arena, biasar, flag);
    poker_prep<true ><<<dim3(9), dim3(256), 0, stream>>>(args, arena, biasar, flag);
    poker_main<false><<<dim3(blocks), dim3(BLK), 0, stream>>>(args, arena, biasar, flag);
    poker_main<true ><<<dim3(blocks), dim3(BLK), 0, stream>>>(args, arena, biasar, flag);
}